// Round 1
// baseline (175.854 us; speedup 1.0000x reference)
//
#include <hip/hip_runtime.h>
#include <hip/hip_bf16.h>

// ---------------- problem constants ----------------
#define Bn    8
#define MO    12
#define Dd    512
#define NOBJ  37
#define NACT  6
#define NTRS  3
#define EMB   128
#define NAA   100
#define NCLS  300
#define Kk    72            // MO*NACT
#define Pp    5112          // Kk*(Kk-1)
#define HALF  768           // Dd + 2*EMB
#define FD    1536          // 2*HALF
#define TPB   512

// output layout (concatenated return order)
#define OUT_FINAL 0
#define OUT_PLOG  (Bn*NCLS)                       // 2400
#define OUT_TTGT  (OUT_PLOG + Bn*Pp*NTRS)         // 125088
#define OUT_ACT   (OUT_TTGT + Bn*Pp*NTRS)         // 247776
#define OUT_OBJ   (OUT_ACT + Bn*MO*NACT)          // 248352

// monotonic float <-> uint mapping for atomicMax-based float max.
// sentinel 0u is below every finite mapped value -> doubles as "empty".
__device__ __forceinline__ unsigned fmap(float f) {
  unsigned u = __float_as_uint(f);
  return (u & 0x80000000u) ? ~u : (u | 0x80000000u);
}
__device__ __forceinline__ float funmap(unsigned u) {
  return __uint_as_float((u & 0x80000000u) ? (u & 0x7fffffffu) : ~u);
}

__device__ __forceinline__ float dot4(const float* __restrict__ a,
                                      const float* __restrict__ b, int n) {
  const float4* a4 = (const float4*)a;
  const float4* b4 = (const float4*)b;
  float acc = 0.f;
#pragma unroll 4
  for (int i = 0; i < (n >> 2); ++i) {
    float4 x = a4[i], y = b4[i];
    acc = fmaf(x.x, y.x, acc);
    acc = fmaf(x.y, y.y, acc);
    acc = fmaf(x.z, y.z, acc);
    acc = fmaf(x.w, y.w, acc);
  }
  return acc;
}

__global__ __launch_bounds__(TPB, 1) void edm_fused(
    const float* __restrict__ inp,      // [B,MO,D]
    const float* __restrict__ objmask,  // [B,MO]
    const float* __restrict__ TRt,      // [B,K,K,3]
    const float* __restrict__ W_obj,    // [NOBJ,D]
    const float* __restrict__ b_obj,
    const float* __restrict__ W_act,    // [NACT,D]
    const float* __restrict__ b_act,
    const float* __restrict__ W_tr,     // [3,FD]
    const float* __restrict__ b_tr,
    const float* __restrict__ W_ne,     // [NCLS,D]
    const float* __restrict__ b_ne,
    const float* __restrict__ obj_emb,  // [NOBJ,EMB]
    const float* __restrict__ act_emb,  // [NACT,EMB]
    const int*   __restrict__ AA,       // [B,K]
    const int*   __restrict__ aalut,    // [NAA,NAA,3]
    float* __restrict__ out)
{
  __shared__ __align__(16) float s_inp[MO * Dd];     // 24 KB
  __shared__ __align__(16) float s_pooled[Dd];
  __shared__ float s_mask[MO];
  __shared__ float s_objout[MO * NOBJ];
  __shared__ float s_actout[MO * NACT];
  __shared__ float s_ne[NCLS];
  __shared__ unsigned s_segmax[NCLS];
  __shared__ float s_L1[Kk * NTRS], s_L2[Kk * NTRS];
  __shared__ float s_inv[NTRS], s_btr[NTRS];
  __shared__ int s_predobj[MO], s_sel[Kk], s_C[Kk], s_aaidx[Kk], s_T;

  const int b = blockIdx.x;
  const int tid = threadIdx.x;

  // ---- Phase 1: stage inp tile + mask, init segmax ----
  for (int idx = tid; idx < MO * Dd; idx += TPB) s_inp[idx] = inp[b * MO * Dd + idx];
  if (tid < MO) s_mask[tid] = objmask[b * MO + tid];
  for (int c = tid; c < NCLS; c += TPB) s_segmax[c] = 0u;
  if (tid < NTRS) s_btr[tid] = b_tr[tid];
  __syncthreads();

  // ---- Phase 2: masked-mean pool (thread = feature dim) ----
  {
    float msum = 0.f, acc = 0.f;
#pragma unroll
    for (int o = 0; o < MO; ++o) {
      float m = s_mask[o];
      msum += m;
      acc = fmaf(s_inp[o * Dd + tid], m, acc);
    }
    s_pooled[tid] = acc / msum;
  }
  __syncthreads();

  // ---- Phase 3: all 512-dots: non_exist (300) + obj_out (444) + act_out (72)
  //               + invalid-logit constants (3). 819 tasks. ----
  for (int task = tid; task < NCLS + MO * NOBJ + MO * NACT + NTRS; task += TPB) {
    if (task < NCLS) {
      int c = task;
      s_ne[c] = dot4(W_ne + c * Dd, s_pooled, Dd) + b_ne[c];
    } else if (task < NCLS + MO * NOBJ) {
      int t2 = task - NCLS;
      int o = t2 / NOBJ, c = t2 - o * NOBJ;
      float v = dot4(W_obj + c * Dd, s_inp + o * Dd, Dd) + b_obj[c];
      s_objout[o * NOBJ + c] = v;
      out[OUT_OBJ + (b * MO + o) * NOBJ + c] = v;
    } else if (task < NCLS + MO * NOBJ + MO * NACT) {
      int t2 = task - NCLS - MO * NOBJ;
      int o = t2 / NACT, a = t2 - o * NACT;
      float v = dot4(W_act + a * Dd, s_inp + o * Dd, Dd) + b_act[a];
      s_actout[o * NACT + a] = v;
      out[OUT_ACT + (b * MO + o) * NACT + a] = v;
    } else {
      int t = task - NCLS - MO * NOBJ - MO * NACT;
      const float4* w4 = (const float4*)(W_tr + t * FD);
      float s = 0.f;
      for (int i2 = 0; i2 < FD / 4; ++i2) {
        float4 x = w4[i2];
        s += x.x + x.y + x.z + x.w;
      }
      s_inv[t] = b_tr[t] - s;   // all-(-1) row logit
    }
  }
  __syncthreads();

  // ---- Phase 4: argmax over obj classes (first-max), selection flags ----
  if (tid < MO) {
    float best = s_objout[tid * NOBJ];
    int bi = 0;
    for (int c = 1; c < NOBJ; ++c) {
      float v = s_objout[tid * NOBJ + c];
      if (v > best) { best = v; bi = c; }
    }
    s_predobj[tid] = bi;
  }
  if (tid < Kk) {
    int o = tid / NACT;
    float act = s_actout[tid];            // layout o*NACT+a == k
    int aa = AA[b * Kk + tid];
    // sigmoid(x) > 0.5  <=>  x > 0 ; pred_act==1.0 also requires mask==1.0
    int sel = (act > 0.f) && (s_mask[o] == 1.0f) && (aa != -1);
    s_sel[tid] = sel;
    s_aaidx[tid] = sel ? aa : -1;
  }
  __syncthreads();

  // ---- Phase 5: prefix counts (thread 0) + per-slot half-logits L1/L2 ----
  if (tid == 0) {
    int c = 0;
    for (int k2 = 0; k2 < Kk; ++k2) { s_C[k2] = c; c += s_sel[k2]; }
    s_T = c;
  }
  // 432 tasks: (half, t, k)
  for (int m = tid; m < Kk * NTRS * 2; m += TPB) {
    int k2 = m % Kk;
    int r = m / Kk;
    int t = r % NTRS;
    int half = r / NTRS;
    int o = k2 / NACT, a = k2 - o * NACT;
    const float* wrow = W_tr + t * FD + half * HALF;
    float v = dot4(wrow, s_inp + o * Dd, Dd)
            + dot4(wrow + Dd, obj_emb + s_predobj[o] * EMB, EMB)
            + dot4(wrow + Dd + EMB, act_emb + a * EMB, EMB);
    if (half) s_L2[k2 * NTRS + t] = v; else s_L1[k2 * NTRS + t] = v;
  }
  __syncthreads();

  // ---- Phase 6: pair loop with closed-form packed destination ----
  const int T = s_T;
  const int Vtot = T * (T - 1);
  float* plog = out + OUT_PLOG + (size_t)b * Pp * NTRS;
  float* ttgt = out + OUT_TTGT + (size_t)b * Pp * NTRS;
  for (int q = tid; q < Pp; q += TPB) {
    int i = q / (Kk - 1);
    int jj = q - i * (Kk - 1);
    int j = jj + (jj >= i ? 1 : 0);
    int si = s_sel[i], sj = s_sel[j];
    // # valid pairs strictly before (i,j) in lex order
    int vb = s_C[i] * (T - 1) + (si ? (s_C[j] - (i < j ? 1 : 0)) : 0);
    bool valid = si && sj;
    int pos = valid ? vb : (Vtot + q - vb);
    float l0, l1, l2;
    if (valid) {
      l0 = s_L1[i * 3 + 0] + s_L2[j * 3 + 0] + s_btr[0];
      l1 = s_L1[i * 3 + 1] + s_L2[j * 3 + 1] + s_btr[1];
      l2 = s_L1[i * 3 + 2] + s_L2[j * 3 + 2] + s_btr[2];
    } else {
      l0 = s_inv[0]; l1 = s_inv[1]; l2 = s_inv[2];
    }
    int ob = pos * 3;
    plog[ob + 0] = l0; plog[ob + 1] = l1; plog[ob + 2] = l2;
    if (valid) {
      const float* tr = TRt + (((size_t)b * Kk + i) * Kk + j) * NTRS;
      ttgt[ob + 0] = tr[0]; ttgt[ob + 1] = tr[1]; ttgt[ob + 2] = tr[2];
      int base = (s_aaidx[i] * NAA + s_aaidx[j]) * NTRS;
      atomicMax(&s_segmax[aalut[base + 0]], fmap(l0));
      atomicMax(&s_segmax[aalut[base + 1]], fmap(l1));
      atomicMax(&s_segmax[aalut[base + 2]], fmap(l2));
    } else {
      ttgt[ob + 0] = -1.f; ttgt[ob + 1] = -1.f; ttgt[ob + 2] = -1.f;
    }
  }
  __syncthreads();

  // ---- Phase 7: final_outputs = exist ? seg_max : non_exist ----
  for (int c = tid; c < NCLS; c += TPB) {
    unsigned u = s_segmax[c];
    out[OUT_FINAL + b * NCLS + c] = u ? funmap(u) : s_ne[c];
  }
}

extern "C" void kernel_launch(void* const* d_in, const int* in_sizes, int n_in,
                              void* d_out, int out_size, void* d_ws, size_t ws_size,
                              hipStream_t stream) {
  (void)in_sizes; (void)n_in; (void)d_ws; (void)ws_size; (void)out_size;
  const float* inp      = (const float*)d_in[0];
  const float* objmask  = (const float*)d_in[1];
  const float* TRt      = (const float*)d_in[2];
  const float* W_obj    = (const float*)d_in[3];
  const float* b_obj    = (const float*)d_in[4];
  const float* W_act    = (const float*)d_in[5];
  const float* b_act    = (const float*)d_in[6];
  const float* W_tr     = (const float*)d_in[7];
  const float* b_tr     = (const float*)d_in[8];
  const float* W_ne     = (const float*)d_in[9];
  const float* b_ne     = (const float*)d_in[10];
  const float* obj_emb  = (const float*)d_in[11];
  const float* act_emb  = (const float*)d_in[12];
  const int*   AA       = (const int*)d_in[13];
  // d_in[14] = obj_act_lookup: eval-branch only, unused
  const int*   aalut    = (const int*)d_in[15];
  float* out = (float*)d_out;

  hipLaunchKernelGGL(edm_fused, dim3(Bn), dim3(TPB), 0, stream,
                     inp, objmask, TRt, W_obj, b_obj, W_act, b_act,
                     W_tr, b_tr, W_ne, b_ne, obj_emb, act_emb, AA, aalut, out);
}

// Round 2
// 97.003 us; speedup vs baseline: 1.8129x; 1.8129x over previous
//
#include <hip/hip_runtime.h>
#include <hip/hip_bf16.h>

// ---------------- problem constants ----------------
#define Bn    8
#define MO    12
#define Dd    512
#define NOBJ  37
#define NACT  6
#define NTRS  3
#define EMB   128
#define NAA   100
#define NCLS  300
#define Kk    72            // MO*NACT
#define Pp    5112          // Kk*(Kk-1)
#define HALF  768           // Dd + 2*EMB
#define FD    1536          // 2*HALF

// output layout (concatenated return order)
#define OUT_FINAL 0
#define OUT_PLOG  (Bn*NCLS)                       // 2400
#define OUT_TTGT  (OUT_PLOG + Bn*Pp*NTRS)         // 125088
#define OUT_ACT   (OUT_TTGT + Bn*Pp*NTRS)         // 247776
#define OUT_OBJ   (OUT_ACT + Bn*Kk)               // 248352

// ---------------- workspace layout (4-byte units) ----------------
#define WS_POOL 0                                 // [B,512] f32 (16B aligned)
#define WS_OBJ  (WS_POOL + Bn*Dd)                 // [B,MO,NOBJ] f32
#define WS_ACT  (WS_OBJ + Bn*MO*NOBJ)             // [B,K] f32
#define WS_LINP (WS_ACT + Bn*Kk)                  // [B,MO,6] f32 (t*2+h)
#define WS_EO   (WS_LINP + Bn*MO*6)               // [NOBJ,6] f32
#define WS_EA   (WS_EO + NOBJ*6)                  // [NACT,6] f32
#define WS_INV  (WS_EA + NACT*6)                  // [3] f32
#define WS_NE   (WS_INV + 6)                      // [B,NCLS] f32 (16B aligned: 9064)
#define WS_SEG  (WS_NE + Bn*NCLS)                 // [B,NCLS] u32
#define WS_PRED (WS_SEG + Bn*NCLS)                // [B,MO] i32
#define WS_SEL  (WS_PRED + Bn*MO)                 // [B,K] i32
#define WS_AAI  (WS_SEL + Bn*Kk)                  // [B,K] i32

// monotonic float <-> uint; 0u is below any finite mapped value = "empty"
__device__ __forceinline__ unsigned fmap(float f) {
  unsigned u = __float_as_uint(f);
  return (u & 0x80000000u) ? ~u : (u | 0x80000000u);
}
__device__ __forceinline__ float funmap(unsigned u) {
  return __uint_as_float((u & 0x80000000u) ? (u & 0x7fffffffu) : ~u);
}

__device__ __forceinline__ float wreduce(float v) {
#pragma unroll
  for (int off = 32; off > 0; off >>= 1) v += __shfl_xor(v, off, 64);
  return v;
}

// 512-length dot, one wave: lane reads float4 #lane and #(lane+64). Conflict-free, coalesced.
__device__ __forceinline__ float dot512_wave(const float* __restrict__ a,
                                             const float* __restrict__ b, int lane) {
  const float4* a4 = (const float4*)a;
  const float4* b4 = (const float4*)b;
  float4 x0 = a4[lane], y0 = b4[lane];
  float4 x1 = a4[lane + 64], y1 = b4[lane + 64];
  float s0 = fmaf(x0.x, y0.x, fmaf(x0.y, y0.y, fmaf(x0.z, y0.z, x0.w * y0.w)));
  float s1 = fmaf(x1.x, y1.x, fmaf(x1.y, y1.y, fmaf(x1.z, y1.z, x1.w * y1.w)));
  return wreduce(s0 + s1);
}

// 128-length dot, one wave: lane reads one float2.
__device__ __forceinline__ float dot128_wave(const float* __restrict__ a,
                                             const float* __restrict__ b, int lane) {
  const float2* a2 = (const float2*)a;
  const float2* b2 = (const float2*)b;
  float2 x = a2[lane], y = b2[lane];
  return wreduce(fmaf(x.x, y.x, x.y * y.y));
}

// ---------------- Kernel A: all argmax/selection-independent dots ----------------
#define AW_OBJ  (Bn*MO*NOBJ)              // 3552 waves
#define AW_ACT  (AW_OBJ + Bn*Kk)          // 4128
#define AW_LINP (AW_ACT + Bn*MO*6)        // 4704
#define AW_EO   (AW_LINP + NOBJ*6)        // 4926
#define AW_EA   (AW_EO + NACT*6)          // 4962
#define AW_INV  (AW_EA + NTRS)            // 4965
#define AW_POOL (AW_INV + Bn*8)           // 5029
#define AW_ZERO (AW_POOL + 38)            // 5067  (ceil(2400/64)=38)

__global__ __launch_bounds__(256) void kA(
    const float* __restrict__ inp, const float* __restrict__ objmask,
    const float* __restrict__ W_obj, const float* __restrict__ b_obj,
    const float* __restrict__ W_act, const float* __restrict__ b_act,
    const float* __restrict__ W_tr, const float* __restrict__ b_tr,
    const float* __restrict__ obj_emb, const float* __restrict__ act_emb,
    float* __restrict__ out, float* __restrict__ ws)
{
  int gt = blockIdx.x * 256 + threadIdx.x;
  int w = gt >> 6, lane = gt & 63;
  if (w < AW_OBJ) {
    int b = w / (MO*NOBJ), r = w % (MO*NOBJ), o = r / NOBJ, c = r % NOBJ;
    float v = dot512_wave(W_obj + c*Dd, inp + (b*MO+o)*Dd, lane) + b_obj[c];
    if (!lane) { out[OUT_OBJ + (b*MO+o)*NOBJ + c] = v; ws[WS_OBJ + (b*MO+o)*NOBJ + c] = v; }
  } else if (w < AW_ACT) {
    int r = w - AW_OBJ, b = r / Kk, k = r % Kk, o = k / NACT, a = k % NACT;
    float v = dot512_wave(W_act + a*Dd, inp + (b*MO+o)*Dd, lane) + b_act[a];
    if (!lane) { out[OUT_ACT + b*Kk + k] = v; ws[WS_ACT + b*Kk + k] = v; }
  } else if (w < AW_LINP) {
    int r = w - AW_ACT, b = r / (MO*6), r2 = r % (MO*6), o = r2 / 6, th = r2 % 6;
    int t = th >> 1, h = th & 1;
    float v = dot512_wave(W_tr + t*FD + h*HALF, inp + (b*MO+o)*Dd, lane);
    if (!lane) ws[WS_LINP + (b*MO+o)*6 + th] = v;
  } else if (w < AW_EO) {
    int r = w - AW_LINP, oc = r / 6, th = r % 6, t = th >> 1, h = th & 1;
    float v = dot128_wave(W_tr + t*FD + h*HALF + Dd, obj_emb + oc*EMB, lane);
    if (!lane) ws[WS_EO + oc*6 + th] = v;
  } else if (w < AW_EA) {
    int r = w - AW_EO, a = r / 6, th = r % 6, t = th >> 1, h = th & 1;
    float v = dot128_wave(W_tr + t*FD + h*HALF + Dd + EMB, act_emb + a*EMB, lane);
    if (!lane) ws[WS_EA + a*6 + th] = v;
  } else if (w < AW_INV) {
    int t = w - AW_EA;
    const float4* w4 = (const float4*)(W_tr + t*FD);
    float s = 0.f;
#pragma unroll
    for (int i = 0; i < 6; ++i) { float4 x = w4[lane + 64*i]; s += x.x + x.y + x.z + x.w; }
    s = wreduce(s);
    if (!lane) ws[WS_INV + t] = b_tr[t] - s;   // all-(-1) pair-row logit
  } else if (w < AW_POOL) {
    int r = w - AW_INV, b = r >> 3, d = (r & 7)*64 + lane;
    float msum = 0.f, acc = 0.f;
#pragma unroll
    for (int o = 0; o < MO; ++o) {
      float m = objmask[b*MO + o];
      msum += m;
      acc = fmaf(inp[(b*MO+o)*Dd + d], m, acc);
    }
    ws[WS_POOL + b*Dd + d] = acc / msum;
  } else if (w < AW_ZERO) {
    int idx = (w - AW_POOL)*64 + lane;
    if (idx < Bn*NCLS) ((unsigned*)ws)[WS_SEG + idx] = 0u;
  }
}

// ---------------- Kernel B: ne dots (need pooled) + argmax + selection ----------------
#define BW_NE (Bn*NCLS)                   // 2400 waves; then 672 thread-tasks (11 waves)

__global__ __launch_bounds__(256) void kB(
    const float* __restrict__ objmask, const int* __restrict__ AA,
    const float* __restrict__ W_ne, const float* __restrict__ b_ne,
    float* __restrict__ ws)
{
  int gt = blockIdx.x * 256 + threadIdx.x;
  int w = gt >> 6, lane = gt & 63;
  if (w < BW_NE) {
    int b = w / NCLS, c = w % NCLS;
    float v = dot512_wave(W_ne + c*Dd, ws + WS_POOL + b*Dd, lane) + b_ne[c];
    if (!lane) ws[WS_NE + b*NCLS + c] = v;
  } else {
    int t2 = gt - BW_NE*64;
    if (t2 < Bn*MO) {                      // obj argmax (first-max)
      int b = t2 / MO, o = t2 % MO;
      const float* p = ws + WS_OBJ + (b*MO+o)*NOBJ;
      float best = p[0]; int bi = 0;
      for (int c = 1; c < NOBJ; ++c) { float v = p[c]; if (v > best) { best = v; bi = c; } }
      ((int*)ws)[WS_PRED + b*MO + o] = bi;
    } else if (t2 < Bn*MO + Bn*Kk) {       // selection flags
      int r = t2 - Bn*MO, b = r / Kk, k = r % Kk, o = k / NACT;
      int aa = AA[b*Kk + k];
      // sigmoid(x)>0.5 <=> x>0 ; pred_act==1.0 also needs mask==1.0
      int sel = (ws[WS_ACT + b*Kk + k] > 0.f) && (objmask[b*MO+o] == 1.0f) && (aa != -1);
      ((int*)ws)[WS_SEL + b*Kk + k] = sel;
      ((int*)ws)[WS_AAI + b*Kk + k] = sel ? aa : -1;
    }
  }
}

// ---------------- Kernel C: pair loop, 20 slices per batch, 1 pair/thread ----------------
#define NSLICE 20

__global__ __launch_bounds__(256) void kC(
    const float* __restrict__ TRt, const float* __restrict__ b_tr,
    const int* __restrict__ aalut,
    float* __restrict__ out, float* __restrict__ ws)
{
  __shared__ float s_L[Kk*6];              // [k][t*2+h], L1 includes b_tr
  __shared__ float s_inv[NTRS];
  __shared__ int s_sel[Kk], s_aa[Kk], s_C[Kk], s_T;

  int b = blockIdx.x / NSLICE, slice = blockIdx.x % NSLICE;
  int tid = threadIdx.x;

  if (tid < Kk) {
    s_sel[tid] = ((const int*)ws)[WS_SEL + b*Kk + tid];
    s_aa[tid]  = ((const int*)ws)[WS_AAI + b*Kk + tid];
  } else if (tid < Kk + NTRS) {
    s_inv[tid - Kk] = ws[WS_INV + (tid - Kk)];
  }
  for (int m = tid; m < Kk*6; m += 256) {  // assemble half-logits
    int k = m / 6, th = m % 6, t = th >> 1, h = th & 1;
    int o = k / NACT, a = k % NACT;
    int po = ((const int*)ws)[WS_PRED + b*MO + o];
    float v = ws[WS_LINP + (b*MO+o)*6 + th] + ws[WS_EO + po*6 + th] + ws[WS_EA + a*6 + th];
    if (h == 0) v += b_tr[t];
    s_L[m] = v;
  }
  __syncthreads();
  if (tid == 0) {
    int c = 0;
    for (int k = 0; k < Kk; ++k) { s_C[k] = c; c += s_sel[k]; }
    s_T = c;
  }
  __syncthreads();

  int T = s_T, Vtot = T*(T-1);
  int q = slice*256 + tid;
  if (q < Pp) {
    float* plog = out + OUT_PLOG + (size_t)b*Pp*NTRS;
    float* ttgt = out + OUT_TTGT + (size_t)b*Pp*NTRS;
    int i = q / (Kk-1);
    int jj = q - i*(Kk-1);
    int j = jj + (jj >= i ? 1 : 0);
    int si = s_sel[i], sj = s_sel[j];
    int vb = s_C[i]*(T-1) + (si ? (s_C[j] - (i < j ? 1 : 0)) : 0);
    bool valid = si && sj;
    int pos = valid ? vb : (Vtot + q - vb);
    float l0, l1, l2;
    if (valid) {
      l0 = s_L[i*6+0] + s_L[j*6+1];
      l1 = s_L[i*6+2] + s_L[j*6+3];
      l2 = s_L[i*6+4] + s_L[j*6+5];
    } else { l0 = s_inv[0]; l1 = s_inv[1]; l2 = s_inv[2]; }
    int ob = pos*3;
    plog[ob+0] = l0; plog[ob+1] = l1; plog[ob+2] = l2;
    if (valid) {
      const float* tr = TRt + (((size_t)b*Kk + i)*Kk + j)*NTRS;
      ttgt[ob+0] = tr[0]; ttgt[ob+1] = tr[1]; ttgt[ob+2] = tr[2];
      int base = (s_aa[i]*NAA + s_aa[j])*NTRS;
      unsigned* seg = (unsigned*)ws + WS_SEG + b*NCLS;
      atomicMax(&seg[aalut[base+0]], fmap(l0));
      atomicMax(&seg[aalut[base+1]], fmap(l1));
      atomicMax(&seg[aalut[base+2]], fmap(l2));
    } else {
      ttgt[ob+0] = -1.f; ttgt[ob+1] = -1.f; ttgt[ob+2] = -1.f;
    }
  }
}

// ---------------- Kernel D: final merge ----------------
__global__ __launch_bounds__(320) void kD(float* __restrict__ out,
                                          const float* __restrict__ ws)
{
  int b = blockIdx.x, c = threadIdx.x;
  if (c < NCLS) {
    unsigned u = ((const unsigned*)ws)[WS_SEG + b*NCLS + c];
    out[OUT_FINAL + b*NCLS + c] = u ? funmap(u) : ws[WS_NE + b*NCLS + c];
  }
}

extern "C" void kernel_launch(void* const* d_in, const int* in_sizes, int n_in,
                              void* d_out, int out_size, void* d_ws, size_t ws_size,
                              hipStream_t stream) {
  (void)in_sizes; (void)n_in; (void)ws_size; (void)out_size;
  const float* inp      = (const float*)d_in[0];
  const float* objmask  = (const float*)d_in[1];
  const float* TRt      = (const float*)d_in[2];
  const float* W_obj    = (const float*)d_in[3];
  const float* b_obj    = (const float*)d_in[4];
  const float* W_act    = (const float*)d_in[5];
  const float* b_act    = (const float*)d_in[6];
  const float* W_tr     = (const float*)d_in[7];
  const float* b_tr     = (const float*)d_in[8];
  const float* W_ne     = (const float*)d_in[9];
  const float* b_ne     = (const float*)d_in[10];
  const float* obj_emb  = (const float*)d_in[11];
  const float* act_emb  = (const float*)d_in[12];
  const int*   AA       = (const int*)d_in[13];
  // d_in[14] = obj_act_lookup (eval-only)
  const int*   aalut    = (const int*)d_in[15];
  float* out = (float*)d_out;
  float* ws  = (float*)d_ws;

  // A: 5067 waves -> 1267 blocks of 4 waves
  hipLaunchKernelGGL(kA, dim3((AW_ZERO + 3) / 4), dim3(256), 0, stream,
                     inp, objmask, W_obj, b_obj, W_act, b_act, W_tr, b_tr,
                     obj_emb, act_emb, out, ws);
  // B: 2411 waves -> 603 blocks
  hipLaunchKernelGGL(kB, dim3((BW_NE + 11 + 3) / 4), dim3(256), 0, stream,
                     objmask, AA, W_ne, b_ne, ws);
  // C: 8 batches x 20 slices
  hipLaunchKernelGGL(kC, dim3(Bn * NSLICE), dim3(256), 0, stream,
                     TRt, b_tr, aalut, out, ws);
  // D: merge
  hipLaunchKernelGGL(kD, dim3(Bn), dim3(320), 0, stream, out, ws);
}